// Round 3
// baseline (162.348 us; speedup 1.0000x reference)
//
#include <hip/hip_runtime.h>
#include <math.h>

#define BATCH 16384

// v3: barrier-free dataflow. conv1 windows read from global via L1 (no xs LDS);
// h1p/h2 are wave-private LDS; only w2 is block-staged. 2 barriers total.
// One wave per sample, 4 samples per 256-thread block.
__global__ __launch_bounds__(256) void qnat_fused(
    const float* __restrict__ x,    // (B,1,28,28)
    const float* __restrict__ w1,   // (4,1,3,3)  uniform -> s_load
    const float* __restrict__ b1,   // (4,)
    const float* __restrict__ w2,   // (4,4,3,3)  lane-varying -> LDS
    const float* __restrict__ b2,   // (4,)
    const float* __restrict__ plw,  // (16,196)
    const float* __restrict__ plb,  // (16,)
    const float* __restrict__ rw,   // (4,4)
    const float* __restrict__ rb,   // (4,)
    float* __restrict__ pre,        // (B,4) pre-BN output (in d_out)
    float* __restrict__ stats)      // [8] {sum_c, sumsq_c}
{
  __shared__ float s_w2[144];
  // per-sample: 4 ch x (16 rows x 20 cols), ch stride 320, +16 slack = 1296 floats.
  // data col c at stored 4+c (16B-aligned b128 writes); rows 0,15 + col pads stay 0.
  __shared__ __align__(16) float h1p[4][1296];
  __shared__ float h2[4][196];
  __shared__ float s_red[4][8];

  const int tid = threadIdx.x;
  const int w = tid >> 6;
  const int lane = tid & 63;
  const int sample = blockIdx.x * 4 + w;

  if (tid < 144) s_w2[tid] = w2[tid];

  // zero h1p (wave-private)
  {
    float4 z4 = make_float4(0.f, 0.f, 0.f, 0.f);
    float4* hz = (float4*)&h1p[w][0];
    #pragma unroll
    for (int t = 0; t < 6; t++) {
      int p = t * 64 + lane;
      if (p < 324) hz[p] = z4;
    }
  }
  __syncthreads();  // s_w2 visible to all waves

  // ---- conv1 + relu + pool: lane = (pooled row i, col-quad q); windows from global/L1 ----
  if (lane < 56) {
    const int i = lane >> 2;            // 0..13
    const int q = lane & 3;             // 0..3
    const float* xb = x + (size_t)sample * 784;
    float win[4][10];                   // win[r][k] <-> input col 8q-1+k
    #pragma unroll
    for (int r = 0; r < 4; r++) {
      int row = 2 * i - 1 + r;
      #pragma unroll
      for (int k = 0; k < 10; k++) win[r][k] = 0.0f;
      if (0 <= row && row < 28) {
        const float* rp = xb + row * 28;
        if (q > 0) win[r][0] = rp[8 * q - 1];
        float4 a = *(const float4*)(rp + 8 * q);
        win[r][1] = a.x; win[r][2] = a.y; win[r][3] = a.z; win[r][4] = a.w;
        if (q < 3) {
          float4 bb = *(const float4*)(rp + 8 * q + 4);
          win[r][5] = bb.x; win[r][6] = bb.y; win[r][7] = bb.z; win[r][8] = bb.w;
          win[r][9] = rp[8 * q + 8];
        }
      }
    }
    float* hb = &h1p[w][20 * (i + 1) + 4 + 4 * q];
    #pragma unroll
    for (int c = 0; c < 4; c++) {
      const float bias = b1[c];
      float m[4];
      #pragma unroll
      for (int jj = 0; jj < 4; jj++) {
        float best = 0.0f;              // relu folded into max
        #pragma unroll
        for (int py = 0; py < 2; py++)
          #pragma unroll
          for (int px = 0; px < 2; px++) {
            float a = bias;
            #pragma unroll
            for (int dy = 0; dy < 3; dy++)
              #pragma unroll
              for (int dx = 0; dx < 3; dx++)
                a = fmaf(win[py + dy][2 * jj + px + dx], w1[c * 9 + dy * 3 + dx], a);
            best = fmaxf(best, a);
          }
        m[jj] = best;
      }
      if (q < 3) *(float4*)(hb + 320 * c) = make_float4(m[0], m[1], m[2], m[3]);
      else       *(float2*)(hb + 320 * c) = make_float2(m[0], m[1]);  // cols 12,13 only
    }
  }
  // h1p is wave-private: no barrier.

  // ---- conv2 + relu + pool: lane = i2*8 + jh*4 + co ----
  if (lane < 56) {
    const int co = lane & 3;
    const int jh = (lane >> 2) & 1;
    const int i2 = lane >> 3;           // 0..6
    float acc[4][2][2];                 // [jj][py][px]
    const float bias2 = b2[co];
    #pragma unroll
    for (int jj = 0; jj < 4; jj++)
      #pragma unroll
      for (int py = 0; py < 2; py++)
        #pragma unroll
        for (int px = 0; px < 2; px++) acc[jj][py][px] = bias2;
    #pragma unroll
    for (int ci = 0; ci < 4; ci++) {
      float win[4][12];                 // win[r][k] <-> input col 8jh+k-2
      #pragma unroll
      for (int r = 0; r < 4; r++) {
        const float2* rp = (const float2*)&h1p[w][320 * ci + 20 * (2 * i2 + r) + 2 + 8 * jh];
        #pragma unroll
        for (int t = 0; t < 6; t++) {
          float2 v = rp[t];
          win[r][2 * t] = v.x; win[r][2 * t + 1] = v.y;
        }
      }
      float wv[9];
      #pragma unroll
      for (int t = 0; t < 9; t++) wv[t] = s_w2[(co * 4 + ci) * 9 + t];
      #pragma unroll
      for (int jj = 0; jj < 4; jj++)
        #pragma unroll
        for (int py = 0; py < 2; py++)
          #pragma unroll
          for (int px = 0; px < 2; px++) {
            float a = acc[jj][py][px];
            #pragma unroll
            for (int dy = 0; dy < 3; dy++)
              #pragma unroll
              for (int dx = 0; dx < 3; dx++)
                a = fmaf(win[py + dy][2 * jj + 1 + px + dx], wv[dy * 3 + dx], a);
            acc[jj][py][px] = a;
          }
    }
    #pragma unroll
    for (int jj = 0; jj < 4; jj++) {
      int J = 4 * jh + jj;
      if (J < 7) {
        float m = fmaxf(fmaxf(acc[jj][0][0], acc[jj][0][1]),
                        fmaxf(acc[jj][1][0], acc[jj][1][1]));
        h2[w][49 * co + 7 * i2 + J] = fmaxf(m, 0.0f);
      }
    }
  }
  // h2 is wave-private: no barrier.

  // ---- linear 196->16 + half-angle sincos (kept in lane registers) ----
  float cv = 0.0f, sv = 0.0f;
  {
    const int k = lane & 15;
    const int part = lane >> 4;
    const float* hh = &h2[w][part * 49];
    const float* wp = plw + k * 196 + part * 49;
    float s = 0.0f;
    #pragma unroll
    for (int f = 0; f < 49; f++) s = fmaf(hh[f], wp[f], s);
    s += __shfl_down(s, 32, 64);
    s += __shfl_down(s, 16, 64);
    if (lane < 16) {
      float pv = s + plb[k];
      __sincosf(pv * 0.5f, &sv, &cv);
    }
  }

  // ---- 4-qubit circuit on lanes 0..15; gate params via shfl broadcast ----
  if (lane < 16) {
    const int l = lane;
    float re = (l == 0) ? 1.0f : 0.0f;
    float im = 0.0f;
    #pragma unroll
    for (int qi = 0; qi < 4; qi++) {
      const int beta = 3 - qi;
      const int m = 1 << beta;
      const int b = (l >> beta) & 1;
      float c = __shfl(cv, 4 * qi, 64), s = __shfl(sv, 4 * qi, 64);
      float pr_ = __shfl_xor(re, m, 64), pi_ = __shfl_xor(im, m, 64);
      float sg = b ? s : -s;
      re = fmaf(c, re, sg * pr_);
      im = fmaf(c, im, sg * pi_);
      c = __shfl(cv, 4 * qi + 1, 64); s = __shfl(sv, 4 * qi + 1, 64);
      float sz = b ? s : -s;
      float nr = c * re - sz * im;
      float ni = c * im + sz * re;
      re = nr; im = ni;
      c = __shfl(cv, 4 * qi + 2, 64); s = __shfl(sv, 4 * qi + 2, 64);
      pr_ = __shfl_xor(re, m, 64); pi_ = __shfl_xor(im, m, 64);
      nr = fmaf(c, re, s * pi_);
      ni = fmaf(c, im, -s * pr_);
      re = nr; im = ni;
      const int tm = 1 << (3 - ((qi + 1) & 3));
      float fr = __shfl_xor(re, tm, 64), fi = __shfl_xor(im, tm, 64);
      if (b) { re = fr; im = fi; }
    }
    float pr2 = re * re + im * im;
    float z0 = ((l >> 3) & 1) ? -pr2 : pr2;
    float z1 = ((l >> 2) & 1) ? -pr2 : pr2;
    float z2 = ((l >> 1) & 1) ? -pr2 : pr2;
    float z3 = (l & 1) ? -pr2 : pr2;
    #pragma unroll
    for (int off = 8; off >= 1; off >>= 1) {
      z0 += __shfl_xor(z0, off, 64);
      z1 += __shfl_xor(z1, off, 64);
      z2 += __shfl_xor(z2, off, 64);
      z3 += __shfl_xor(z3, off, 64);
    }
    if (l == 0) {
      float o0 = fmaf(rw[0],  z0, fmaf(rw[1],  z1, fmaf(rw[2],  z2, fmaf(rw[3],  z3, rb[0]))));
      float o1 = fmaf(rw[4],  z0, fmaf(rw[5],  z1, fmaf(rw[6],  z2, fmaf(rw[7],  z3, rb[1]))));
      float o2 = fmaf(rw[8],  z0, fmaf(rw[9],  z1, fmaf(rw[10], z2, fmaf(rw[11], z3, rb[2]))));
      float o3 = fmaf(rw[12], z0, fmaf(rw[13], z1, fmaf(rw[14], z2, fmaf(rw[15], z3, rb[3]))));
      *(float4*)(pre + (size_t)sample * 4) = make_float4(o0, o1, o2, o3);
      s_red[w][0] = o0; s_red[w][4] = o0 * o0;
      s_red[w][1] = o1; s_red[w][5] = o1 * o1;
      s_red[w][2] = o2; s_red[w][6] = o2 * o2;
      s_red[w][3] = o3; s_red[w][7] = o3 * o3;
    }
  }
  __syncthreads();
  if (tid < 8) {
    float v = s_red[0][tid] + s_red[1][tid] + s_red[2][tid] + s_red[3][tid];
    atomicAdd(&stats[tid], v);
  }
}

__global__ __launch_bounds__(256) void qnat_bn(
    float* __restrict__ pre,
    const float* __restrict__ stats,
    const float* __restrict__ bnw,
    const float* __restrict__ bnb)
{
  int idx = blockIdx.x * 256 + threadIdx.x;
  int c = idx & 3;
  float mean = stats[c] * (1.0f / BATCH);
  float ex2 = stats[4 + c] * (1.0f / BATCH);
  float var = ex2 - mean * mean;
  float inv = rsqrtf(var + 1e-5f);
  pre[idx] = (pre[idx] - mean) * inv * bnw[c] + bnb[c];
}

extern "C" void kernel_launch(void* const* d_in, const int* in_sizes, int n_in,
                              void* d_out, int out_size, void* d_ws, size_t ws_size,
                              hipStream_t stream) {
  const float* x   = (const float*)d_in[0];
  const float* w1  = (const float*)d_in[1];
  const float* b1  = (const float*)d_in[2];
  const float* w2  = (const float*)d_in[3];
  const float* b2  = (const float*)d_in[4];
  const float* plw = (const float*)d_in[5];
  const float* plb = (const float*)d_in[6];
  const float* rw  = (const float*)d_in[7];
  const float* rb  = (const float*)d_in[8];
  const float* bnw = (const float*)d_in[9];
  const float* bnb = (const float*)d_in[10];

  float* out   = (float*)d_out;
  float* stats = (float*)d_ws;

  hipMemsetAsync(stats, 0, 8 * sizeof(float), stream);
  qnat_fused<<<BATCH / 4, 256, 0, stream>>>(x, w1, b1, w2, b2, plw, plb, rw, rb, out, stats);
  qnat_bn<<<(BATCH * 4) / 256, 256, 0, stream>>>(out, stats, bnw, bnb);
}

// Round 4
// 156.950 us; speedup vs baseline: 1.0344x; 1.0344x over previous
//
#include <hip/hip_runtime.h>
#include <math.h>

#define BATCH 16384

// v4: conv2 one-lane-per-output (32 b64 loads vs 96), all weights via scalar
// loads (no LDS weight staging), odd-base h1p layout for aligned b64 windows,
// h2 stride 52 for b128 linear-phase reads. One barrier total.
__global__ __launch_bounds__(256) void qnat_fused(
    const float* __restrict__ x,    // (B,1,28,28)
    const float* __restrict__ w1,   // (4,1,3,3)  uniform -> s_load
    const float* __restrict__ b1,   // (4,)
    const float* __restrict__ w2,   // (4,4,3,3)  uniform -> s_load
    const float* __restrict__ b2,   // (4,)
    const float* __restrict__ plw,  // (16,196)
    const float* __restrict__ plb,  // (16,)
    const float* __restrict__ rw,   // (4,4)
    const float* __restrict__ rb,   // (4,)
    float* __restrict__ pre,        // (B,4) pre-BN output (in d_out)
    float* __restrict__ stats)      // [8] {sum_c, sumsq_c}
{
  // per-sample h1p: 4 ch x (16 rows x 18 cols), ch stride 288; data col c at
  // stored c+1 (rows 0,15 and cols 0,15 are zero pads; 16,17 slack).
  __shared__ __align__(16) float h1p[4][4 * 288 + 16];
  __shared__ __align__(16) float h2[4][212];   // ch stride 52 (49 data + 3 pad)
  __shared__ float s_red[4][8];

  const int tid = threadIdx.x;
  const int w = tid >> 6;
  const int lane = tid & 63;
  const int sample = blockIdx.x * 4 + w;

  // ---- zero h1p (wave-private; no barrier needed) ----
  {
    float4 z4 = make_float4(0.f, 0.f, 0.f, 0.f);
    float4* hz = (float4*)&h1p[w][0];
    #pragma unroll
    for (int t = 0; t < 5; t++) {
      int p = t * 64 + lane;
      if (p < 292) hz[p] = z4;
    }
  }

  // ---- conv1 + relu + pool: lane = (pooled row i, col-quad q) ----
  if (lane < 56) {
    const int i = lane >> 2;            // 0..13
    const int q = lane & 3;             // 0..3
    const float* xb = x + (size_t)sample * 784;
    float win[4][10];                   // win[r][k] <-> input col 8q-1+k
    #pragma unroll
    for (int r = 0; r < 4; r++) {
      int row = 2 * i - 1 + r;
      #pragma unroll
      for (int k = 0; k < 10; k++) win[r][k] = 0.0f;
      if (0 <= row && row < 28) {
        const float* rp = xb + row * 28;
        if (q > 0) win[r][0] = rp[8 * q - 1];
        float4 a = *(const float4*)(rp + 8 * q);
        win[r][1] = a.x; win[r][2] = a.y; win[r][3] = a.z; win[r][4] = a.w;
        if (q < 3) {
          float4 bb = *(const float4*)(rp + 8 * q + 4);
          win[r][5] = bb.x; win[r][6] = bb.y; win[r][7] = bb.z; win[r][8] = bb.w;
          win[r][9] = rp[8 * q + 8];
        }
      }
    }
    float* hb = &h1p[w][18 * (i + 1) + 1 + 4 * q];
    #pragma unroll
    for (int c = 0; c < 4; c++) {
      const float bias = b1[c];
      float m[4];
      #pragma unroll
      for (int jj = 0; jj < 4; jj++) {
        float best = 0.0f;              // relu folded into max
        #pragma unroll
        for (int py = 0; py < 2; py++)
          #pragma unroll
          for (int px = 0; px < 2; px++) {
            float a = bias;
            #pragma unroll
            for (int dy = 0; dy < 3; dy++)
              #pragma unroll
              for (int dx = 0; dx < 3; dx++)
                a = fmaf(win[py + dy][2 * jj + px + dx], w1[c * 9 + dy * 3 + dx], a);
            best = fmaxf(best, a);
          }
        m[jj] = best;
      }
      float* p = hb + 288 * c;
      if (q < 3) {
        p[0] = m[0];
        *(float2*)(p + 1) = make_float2(m[1], m[2]);  // stored 2+4q: even -> b64
        p[3] = m[3];
      } else {
        p[0] = m[0];                    // cols 12,13 only
        p[1] = m[1];
      }
    }
  }
  // h1p wave-private: no barrier.

  // ---- conv2 + relu + pool: one lane per pooled output (i2, jq) ----
  {
    const int jq = lane & 7;            // 0..6 valid
    const int i2 = lane >> 3;           // 0..6 valid
    if (i2 < 7 && jq < 7) {
      float win[4][4][4];               // [ci][r][k], k <-> data col 2jq-1+k
      #pragma unroll
      for (int ci = 0; ci < 4; ci++) {
        const float* rp = &h1p[w][288 * ci + 18 * (2 * i2) + 2 * jq];
        #pragma unroll
        for (int r = 0; r < 4; r++) {
          float2 a = *(const float2*)(rp + 18 * r);
          float2 b = *(const float2*)(rp + 18 * r + 2);
          win[ci][r][0] = a.x; win[ci][r][1] = a.y;
          win[ci][r][2] = b.x; win[ci][r][3] = b.y;
        }
      }
      #pragma unroll
      for (int co = 0; co < 4; co++) {
        const float bias = b2[co];
        float a00 = bias, a01 = bias, a10 = bias, a11 = bias;
        #pragma unroll
        for (int ci = 0; ci < 4; ci++) {
          #pragma unroll
          for (int dy = 0; dy < 3; dy++)
            #pragma unroll
            for (int dx = 0; dx < 3; dx++) {
              const float ww = w2[(co * 4 + ci) * 9 + dy * 3 + dx];
              a00 = fmaf(win[ci][dy][dx],         ww, a00);
              a01 = fmaf(win[ci][dy][dx + 1],     ww, a01);
              a10 = fmaf(win[ci][dy + 1][dx],     ww, a10);
              a11 = fmaf(win[ci][dy + 1][dx + 1], ww, a11);
            }
        }
        float m = fmaxf(fmaxf(a00, a01), fmaxf(a10, a11));
        h2[w][52 * co + 7 * i2 + jq] = fmaxf(m, 0.0f);
      }
    }
  }
  // h2 wave-private: no barrier.

  // ---- linear 196->16 + half-angle sincos ----
  float cv = 0.0f, sv = 0.0f;
  {
    const int k = lane & 15;
    const int part = lane >> 4;
    const float* hh = &h2[w][52 * part];         // 49 values, 16B-aligned
    const float* wp = plw + k * 196 + part * 49; // 49 values (L1-resident)
    float s = 0.0f;
    #pragma unroll
    for (int t = 0; t < 12; t++) {
      float4 hv = *(const float4*)(hh + 4 * t);
      s = fmaf(hv.x, wp[4 * t + 0], s);
      s = fmaf(hv.y, wp[4 * t + 1], s);
      s = fmaf(hv.z, wp[4 * t + 2], s);
      s = fmaf(hv.w, wp[4 * t + 3], s);
    }
    s = fmaf(hh[48], wp[48], s);
    s += __shfl_down(s, 32, 64);
    s += __shfl_down(s, 16, 64);
    if (lane < 16) {
      float pv = s + plb[k];
      __sincosf(pv * 0.5f, &sv, &cv);
    }
  }

  // ---- 4-qubit circuit on lanes 0..15; gate params via shfl broadcast ----
  if (lane < 16) {
    const int l = lane;
    float re = (l == 0) ? 1.0f : 0.0f;
    float im = 0.0f;
    #pragma unroll
    for (int qi = 0; qi < 4; qi++) {
      const int beta = 3 - qi;
      const int m = 1 << beta;
      const int b = (l >> beta) & 1;
      float c = __shfl(cv, 4 * qi, 64), s = __shfl(sv, 4 * qi, 64);
      float pr_ = __shfl_xor(re, m, 64), pi_ = __shfl_xor(im, m, 64);
      float sg = b ? s : -s;
      re = fmaf(c, re, sg * pr_);
      im = fmaf(c, im, sg * pi_);
      c = __shfl(cv, 4 * qi + 1, 64); s = __shfl(sv, 4 * qi + 1, 64);
      float sz = b ? s : -s;
      float nr = c * re - sz * im;
      float ni = c * im + sz * re;
      re = nr; im = ni;
      c = __shfl(cv, 4 * qi + 2, 64); s = __shfl(sv, 4 * qi + 2, 64);
      pr_ = __shfl_xor(re, m, 64); pi_ = __shfl_xor(im, m, 64);
      nr = fmaf(c, re, s * pi_);
      ni = fmaf(c, im, -s * pr_);
      re = nr; im = ni;
      const int tm = 1 << (3 - ((qi + 1) & 3));
      float fr = __shfl_xor(re, tm, 64), fi = __shfl_xor(im, tm, 64);
      if (b) { re = fr; im = fi; }
    }
    float pr2 = re * re + im * im;
    float z0 = ((l >> 3) & 1) ? -pr2 : pr2;
    float z1 = ((l >> 2) & 1) ? -pr2 : pr2;
    float z2 = ((l >> 1) & 1) ? -pr2 : pr2;
    float z3 = (l & 1) ? -pr2 : pr2;
    #pragma unroll
    for (int off = 8; off >= 1; off >>= 1) {
      z0 += __shfl_xor(z0, off, 64);
      z1 += __shfl_xor(z1, off, 64);
      z2 += __shfl_xor(z2, off, 64);
      z3 += __shfl_xor(z3, off, 64);
    }
    if (l == 0) {
      float o0 = fmaf(rw[0],  z0, fmaf(rw[1],  z1, fmaf(rw[2],  z2, fmaf(rw[3],  z3, rb[0]))));
      float o1 = fmaf(rw[4],  z0, fmaf(rw[5],  z1, fmaf(rw[6],  z2, fmaf(rw[7],  z3, rb[1]))));
      float o2 = fmaf(rw[8],  z0, fmaf(rw[9],  z1, fmaf(rw[10], z2, fmaf(rw[11], z3, rb[2]))));
      float o3 = fmaf(rw[12], z0, fmaf(rw[13], z1, fmaf(rw[14], z2, fmaf(rw[15], z3, rb[3]))));
      *(float4*)(pre + (size_t)sample * 4) = make_float4(o0, o1, o2, o3);
      s_red[w][0] = o0; s_red[w][4] = o0 * o0;
      s_red[w][1] = o1; s_red[w][5] = o1 * o1;
      s_red[w][2] = o2; s_red[w][6] = o2 * o2;
      s_red[w][3] = o3; s_red[w][7] = o3 * o3;
    }
  }
  __syncthreads();
  if (tid < 8) {
    float v = s_red[0][tid] + s_red[1][tid] + s_red[2][tid] + s_red[3][tid];
    atomicAdd(&stats[tid], v);
  }
}

__global__ __launch_bounds__(256) void qnat_bn(
    float* __restrict__ pre,
    const float* __restrict__ stats,
    const float* __restrict__ bnw,
    const float* __restrict__ bnb)
{
  int idx = blockIdx.x * 256 + threadIdx.x;
  int c = idx & 3;
  float mean = stats[c] * (1.0f / BATCH);
  float ex2 = stats[4 + c] * (1.0f / BATCH);
  float var = ex2 - mean * mean;
  float inv = rsqrtf(var + 1e-5f);
  pre[idx] = (pre[idx] - mean) * inv * bnw[c] + bnb[c];
}

extern "C" void kernel_launch(void* const* d_in, const int* in_sizes, int n_in,
                              void* d_out, int out_size, void* d_ws, size_t ws_size,
                              hipStream_t stream) {
  const float* x   = (const float*)d_in[0];
  const float* w1  = (const float*)d_in[1];
  const float* b1  = (const float*)d_in[2];
  const float* w2  = (const float*)d_in[3];
  const float* b2  = (const float*)d_in[4];
  const float* plw = (const float*)d_in[5];
  const float* plb = (const float*)d_in[6];
  const float* rw  = (const float*)d_in[7];
  const float* rb  = (const float*)d_in[8];
  const float* bnw = (const float*)d_in[9];
  const float* bnb = (const float*)d_in[10];

  float* out   = (float*)d_out;
  float* stats = (float*)d_ws;

  hipMemsetAsync(stats, 0, 8 * sizeof(float), stream);
  qnat_fused<<<BATCH / 4, 256, 0, stream>>>(x, w1, b1, w2, b2, plw, plb, rw, rb, out, stats);
  qnat_bn<<<(BATCH * 4) / 256, 256, 0, stream>>>(out, stats, bnw, bnb);
}